// Round 1
// baseline (256.882 us; speedup 1.0000x reference)
//
#include <hip/hip_runtime.h>
#include <hip/hip_bf16.h>
#include <cstdint>

#define B_ 8
#define T_ 2048
#define C_ 1024
#define H_ 64
#define BT_ (B_ * T_)

typedef float4 f4;

// ---------------------------------------------------------------------------
// Projection: x[BT,1024] @ {Wk,Wq,Wv}[1024,64] -> Kp,Qp,Vp [BT,64]  (fp32)
// 256 blocks x 256 threads. Tile: 64 rows x 192 cols (all three W), Kc=32.
// Micro-tile per thread: 4 rows x (3 mats x 4 cols). x tile XOR-swizzled f4.
// ---------------------------------------------------------------------------
__global__ __launch_bounds__(256) void proj_kernel(
    const float* __restrict__ x,  const float* __restrict__ Wk,
    const float* __restrict__ Wq, const float* __restrict__ Wv,
    float* __restrict__ Kp, float* __restrict__ Qp, float* __restrict__ Vp) {
  __shared__ f4 xs4[64 * 8];       // 64 rows x 32 k  (8 f4/row), swizzled
  __shared__ f4 ws4[3 * 32 * 16];  // 3 mats x 32 k x 64 cols (16 f4/row)
  const int t  = threadIdx.x;
  const int tx = t & 15, ty = t >> 4;
  const int rowBase = blockIdx.x * 64;

  f4 acc[4][3];
#pragma unroll
  for (int i = 0; i < 4; ++i)
#pragma unroll
    for (int w = 0; w < 3; ++w) acc[i][w] = f4{0.f, 0.f, 0.f, 0.f};

  for (int k0 = 0; k0 < C_; k0 += 32) {
    __syncthreads();
    // x tile: 64 rows x 8 f4, 2 f4/thread, coalesced, swizzled store
#pragma unroll
    for (int j = 0; j < 2; ++j) {
      int u = t + 256 * j;
      int r = u >> 3, f = u & 7;
      xs4[r * 8 + (f ^ (r & 7))] =
          *reinterpret_cast<const f4*>(&x[(size_t)(rowBase + r) * C_ + k0 + f * 4]);
    }
    // W tiles: 3 x (32 x 16 f4), 6 f4/thread; mat index compile-time per j
#pragma unroll
    for (int j = 0; j < 6; ++j) {
      const float* W = (j < 2) ? Wk : (j < 4) ? Wq : Wv;
      int rem = t + 256 * (j & 1);
      int kk = rem >> 4, f = rem & 15;
      ws4[(j >> 1) * 512 + rem] =
          *reinterpret_cast<const f4*>(&W[(size_t)(k0 + kk) * H_ + f * 4]);
    }
    __syncthreads();

#pragma unroll
    for (int f = 0; f < 8; ++f) {
      f4 xv[4];
#pragma unroll
      for (int i = 0; i < 4; ++i) {
        int r = ty + 16 * i;                      // (r & 7) == (ty & 7)
        xv[i] = xs4[r * 8 + (f ^ (ty & 7))];
      }
#pragma unroll
      for (int w = 0; w < 3; ++w) {
#pragma unroll
        for (int kk = 0; kk < 4; ++kk) {
          f4 wv = ws4[(w * 32 + f * 4 + kk) * 16 + tx];
#pragma unroll
          for (int i = 0; i < 4; ++i) {
            float xk = (kk == 0) ? xv[i].x : (kk == 1) ? xv[i].y
                      : (kk == 2) ? xv[i].z : xv[i].w;
            acc[i][w].x += xk * wv.x;
            acc[i][w].y += xk * wv.y;
            acc[i][w].z += xk * wv.z;
            acc[i][w].w += xk * wv.w;
          }
        }
      }
    }
  }

#pragma unroll
  for (int w = 0; w < 3; ++w) {
    float* O = (w == 0) ? Kp : (w == 1) ? Qp : Vp;
#pragma unroll
    for (int i = 0; i < 4; ++i) {
      int row = rowBase + ty + 16 * i;
      *reinterpret_cast<f4*>(&O[(size_t)row * H_ + tx * 4]) = acc[i][w];
    }
  }
}

// ---------------------------------------------------------------------------
// Causal flash attention (fp32). Attention-query = k-projection, key = q-proj.
// 256 blocks x 256 threads; block handles paired q-tiles (a, 63-a) of 32 rows
// -> uniform 65 key-tiles of 32 per block. 2x2 micro, online softmax.
// ---------------------------------------------------------------------------
__global__ __launch_bounds__(256) void attn_kernel(
    const float* __restrict__ Qa, const float* __restrict__ Ka,
    const float* __restrict__ Va, float* __restrict__ out) {
  __shared__ f4 Qs[32 * 16];   // 32 rows x 64 dims, swizzled f4
  __shared__ f4 Ks[32 * 16];
  __shared__ f4 Vs[32 * 16];
  __shared__ float Ps[32 * 33];

  const int t  = threadIdx.x;
  const int tx = t & 15, ty = t >> 4;
  const int bb = blockIdx.x >> 5;
  const int a  = blockIdx.x & 31;
  const float* Qb = Qa + (size_t)bb * T_ * H_;
  const float* Kb = Ka + (size_t)bb * T_ * H_;
  const float* Vb = Va + (size_t)bb * T_ * H_;
  const int r0 = ty, r1 = ty + 16;
  const int c0 = tx, c1 = tx + 16;

#pragma unroll 1
  for (int half = 0; half < 2; ++half) {
    const int qt = half ? (63 - a) : a;
    const int qbase = qt * 32;
    __syncthreads();  // previous half's readers of Qs are done
#pragma unroll
    for (int j = 0; j < 2; ++j) {
      int u = t + 256 * j, r = u >> 4, f = u & 15;
      Qs[r * 16 + (f ^ (r & 7))] =
          *reinterpret_cast<const f4*>(&Qb[(size_t)(qbase + r) * H_ + f * 4]);
    }
    f4 o0 = {0.f, 0.f, 0.f, 0.f}, o1 = {0.f, 0.f, 0.f, 0.f};
    float m0 = -1e30f, m1 = -1e30f, l0 = 0.f, l1 = 0.f;

    for (int kt = 0; kt <= qt; ++kt) {
      const int kbase = kt * 32;
      __syncthreads();  // prev PV done reading Vs/Ps; Qs stores drained too
#pragma unroll
      for (int j = 0; j < 2; ++j) {
        int u = t + 256 * j, r = u >> 4, f = u & 15;
        Ks[r * 16 + (f ^ (r & 7))] =
            *reinterpret_cast<const f4*>(&Kb[(size_t)(kbase + r) * H_ + f * 4]);
        Vs[r * 16 + (f ^ (r & 7))] =
            *reinterpret_cast<const f4*>(&Vb[(size_t)(kbase + r) * H_ + f * 4]);
      }
      __syncthreads();

      float s00 = 0.f, s01 = 0.f, s10 = 0.f, s11 = 0.f;
#pragma unroll
      for (int f = 0; f < 16; ++f) {
        f4 q0 = Qs[r0 * 16 + (f ^ (r0 & 7))];
        f4 q1 = Qs[r1 * 16 + (f ^ (r1 & 7))];
        f4 k0v = Ks[c0 * 16 + (f ^ (c0 & 7))];
        f4 k1v = Ks[c1 * 16 + (f ^ (c1 & 7))];
        s00 += q0.x * k0v.x + q0.y * k0v.y + q0.z * k0v.z + q0.w * k0v.w;
        s01 += q0.x * k1v.x + q0.y * k1v.y + q0.z * k1v.z + q0.w * k1v.w;
        s10 += q1.x * k0v.x + q1.y * k0v.y + q1.z * k0v.z + q1.w * k0v.w;
        s11 += q1.x * k1v.x + q1.y * k1v.y + q1.z * k1v.z + q1.w * k1v.w;
      }
      const float sc = 0.03125f;  // 1024^-0.5
      s00 *= sc; s01 *= sc; s10 *= sc; s11 *= sc;
      if (kt == qt) {  // causal mask on diagonal tile only
        int i0 = qbase + r0, i1 = qbase + r1;
        if (kbase + c0 > i0) s00 = -1e30f;
        if (kbase + c1 > i0) s01 = -1e30f;
        if (kbase + c0 > i1) s10 = -1e30f;
        if (kbase + c1 > i1) s11 = -1e30f;
      }
      // row reductions across the 16 tx lanes (same ty group within wave)
      float mx0 = fmaxf(s00, s01), mx1 = fmaxf(s10, s11);
#pragma unroll
      for (int d = 1; d < 16; d <<= 1) {
        mx0 = fmaxf(mx0, __shfl_xor(mx0, d));
        mx1 = fmaxf(mx1, __shfl_xor(mx1, d));
      }
      float mn0 = fmaxf(m0, mx0), mn1 = fmaxf(m1, mx1);
      float p00 = __expf(s00 - mn0), p01 = __expf(s01 - mn0);
      float p10 = __expf(s10 - mn1), p11 = __expf(s11 - mn1);
      float su0 = p00 + p01, su1 = p10 + p11;
#pragma unroll
      for (int d = 1; d < 16; d <<= 1) {
        su0 += __shfl_xor(su0, d);
        su1 += __shfl_xor(su1, d);
      }
      float e0 = __expf(m0 - mn0), e1 = __expf(m1 - mn1);
      l0 = l0 * e0 + su0;  l1 = l1 * e1 + su1;
      o0.x *= e0; o0.y *= e0; o0.z *= e0; o0.w *= e0;
      o1.x *= e1; o1.y *= e1; o1.z *= e1; o1.w *= e1;
      m0 = mn0; m1 = mn1;
      Ps[r0 * 33 + c0] = p00; Ps[r0 * 33 + c1] = p01;
      Ps[r1 * 33 + c0] = p10; Ps[r1 * 33 + c1] = p11;
      __syncthreads();
#pragma unroll
      for (int c = 0; c < 32; ++c) {
        f4 vv = Vs[c * 16 + (tx ^ (c & 7))];
        float p0 = Ps[r0 * 33 + c], p1 = Ps[r1 * 33 + c];
        o0.x += p0 * vv.x; o0.y += p0 * vv.y; o0.z += p0 * vv.z; o0.w += p0 * vv.w;
        o1.x += p1 * vv.x; o1.y += p1 * vv.y; o1.z += p1 * vv.z; o1.w += p1 * vv.w;
      }
    }
    float iv0 = 1.f / l0, iv1 = 1.f / l1;
    f4 w0 = {o0.x * iv0, o0.y * iv0, o0.z * iv0, o0.w * iv0};
    f4 w1 = {o1.x * iv1, o1.y * iv1, o1.z * iv1, o1.w * iv1};
    *reinterpret_cast<f4*>(&out[((size_t)bb * T_ + qbase + r0) * H_ + tx * 4]) = w0;
    *reinterpret_cast<f4*>(&out[((size_t)bb * T_ + qbase + r1) * H_ + tx * 4]) = w1;
  }
}

extern "C" void kernel_launch(void* const* d_in, const int* in_sizes, int n_in,
                              void* d_out, int out_size, void* d_ws, size_t ws_size,
                              hipStream_t stream) {
  const float* x  = (const float*)d_in[0];
  const float* Wk = (const float*)d_in[1];
  const float* Wq = (const float*)d_in[2];
  const float* Wv = (const float*)d_in[3];
  float* out = (float*)d_out;

  float* Kp = (float*)d_ws;                 // [BT,64] fp32
  float* Qp = Kp + (size_t)BT_ * H_;
  float* Vp = Qp + (size_t)BT_ * H_;        // total 12 MB of d_ws

  hipLaunchKernelGGL(proj_kernel, dim3(BT_ / 64), dim3(256), 0, stream,
                     x, Wk, Wq, Wv, Kp, Qp, Vp);
  // source quirk: attention-query = k-projection, attention-key = q-projection
  hipLaunchKernelGGL(attn_kernel, dim3(256), dim3(256), 0, stream,
                     Kp, Qp, Vp, out);
}

// Round 2
// 87.323 us; speedup vs baseline: 2.9418x; 2.9418x over previous
//
#include <hip/hip_runtime.h>
#include <cstdint>

#define B_ 8
#define T_ 2048
#define C_ 1024
#define H_ 64
#define BT_ (B_ * T_)

typedef short short8 __attribute__((ext_vector_type(8)));
typedef float f32x4 __attribute__((ext_vector_type(4)));

__device__ inline short f2bf(float f) {
  uint32_t u = __float_as_uint(f);
  u += 0x7fffu + ((u >> 16) & 1u);   // RNE; inputs are finite
  return (short)(u >> 16);
}

// ---------------------------------------------------------------------------
// prep_w: Wk/Wq/Wv [1024][64] fp32 -> Wt [192][1024] bf16 (transposed, n-major)
// 48 blocks (3 mats x 16 k-chunks) x 256 threads.
// ---------------------------------------------------------------------------
__global__ __launch_bounds__(256) void prep_w(
    const float* __restrict__ Wk, const float* __restrict__ Wq,
    const float* __restrict__ Wv, short* __restrict__ Wt) {
  __shared__ float wl[64][68];
  const int mat = blockIdx.x >> 4;
  const int kc = blockIdx.x & 15;
  const float* W = (mat == 0) ? Wk : (mat == 1) ? Wq : Wv;
  const int t = threadIdx.x;
  const int k0 = kc * 64;
#pragma unroll
  for (int j = 0; j < 4; ++j) {
    int s = t + 256 * j;
    int kr = s >> 4, cf = s & 15;
    float4 v = *reinterpret_cast<const float4*>(&W[(size_t)(k0 + kr) * H_ + cf * 4]);
    wl[kr][cf * 4 + 0] = v.x; wl[kr][cf * 4 + 1] = v.y;
    wl[kr][cf * 4 + 2] = v.z; wl[kr][cf * 4 + 3] = v.w;
  }
  __syncthreads();
#pragma unroll
  for (int j = 0; j < 2; ++j) {
    int s = t + 256 * j;
    int n = s >> 3, g = s & 7;
    short8 o;
#pragma unroll
    for (int i = 0; i < 8; ++i) o[i] = f2bf(wl[8 * g + i][n]);
    *reinterpret_cast<short8*>(&Wt[(size_t)(mat * 64 + n) * C_ + k0 + 8 * g]) = o;
  }
}

// ---------------------------------------------------------------------------
// proj: x[16384][1024] fp32 @ Wt -> Kp,Qp [BT][64] bf16, Vt [8][64][2048] bf16
// 512 blocks x 128 thr (2 waves). Block: 32 rows x 192 cols. K-chunk 64,
// double-buffered LDS (x reg-prefetched, converted to bf16; W bf16 restaged).
// MFMA 16x16x32 bf16; wave w owns rows 16w..16w+15 (1 m-tile x 12 n-tiles).
// ---------------------------------------------------------------------------
__global__ __launch_bounds__(128) void proj_kernel(
    const float* __restrict__ x, const short* __restrict__ Wt,
    short* __restrict__ Kp, short* __restrict__ Qp, short* __restrict__ Vt) {
  __shared__ short xs[2][32 * 64];    // 4KB each, XOR-swizzled 16B slots
  __shared__ short ws[2][192 * 64];   // 24KB each, XOR-swizzled 16B slots
  const int t = threadIdx.x;
  const int lane = t & 63, w = t >> 6;
  const int l15 = lane & 15, lg = lane >> 4;
  const int rbase = blockIdx.x * 32;

  // x staging: thread covers row xr, 16 consecutive fp32 at col (t&3)*16
  const int xr = t >> 2;
  const int xg0 = (t & 3) * 2;  // first 8-elem slot
  const float* xsrc = &x[(size_t)(rbase + xr) * C_ + (t & 3) * 16];

  f32x4 acc[12];
  const f32x4 zf = {0.f, 0.f, 0.f, 0.f};
#pragma unroll
  for (int i = 0; i < 12; ++i) acc[i] = zf;

  // ---- prologue: stage chunk 0 into buffer 0 ----
  {
#pragma unroll
    for (int half = 0; half < 2; ++half) {
      float4 v0 = *reinterpret_cast<const float4*>(xsrc + half * 8);
      float4 v1 = *reinterpret_cast<const float4*>(xsrc + half * 8 + 4);
      short8 o;
      o[0] = f2bf(v0.x); o[1] = f2bf(v0.y); o[2] = f2bf(v0.z); o[3] = f2bf(v0.w);
      o[4] = f2bf(v1.x); o[5] = f2bf(v1.y); o[6] = f2bf(v1.z); o[7] = f2bf(v1.w);
      int g = xg0 + half;
      *reinterpret_cast<short8*>(&xs[0][xr * 64 + ((g ^ (xr & 7)) * 8)]) = o;
    }
#pragma unroll
    for (int j = 0; j < 12; ++j) {
      int s = t + 128 * j;
      int n2 = s >> 3, g = s & 7;
      short8 v = *reinterpret_cast<const short8*>(&Wt[(size_t)n2 * C_ + 8 * g]);
      *reinterpret_cast<short8*>(&ws[0][n2 * 64 + ((g ^ (n2 & 7)) * 8)]) = v;
    }
  }

  for (int it = 0; it < 16; ++it) {
    __syncthreads();
    const int cb = it & 1, nb = cb ^ 1;
    // prefetch next x into regs; restage next W (into the free buffer)
    float4 xr4[4];
    if (it < 15) {
      const int k1 = (it + 1) * 64;
#pragma unroll
      for (int j = 0; j < 4; ++j)
        xr4[j] = *reinterpret_cast<const float4*>(xsrc + k1 + j * 4);
#pragma unroll
      for (int j = 0; j < 12; ++j) {
        int s = t + 128 * j;
        int n2 = s >> 3, g = s & 7;
        short8 v = *reinterpret_cast<const short8*>(&Wt[(size_t)n2 * C_ + k1 + 8 * g]);
        *reinterpret_cast<short8*>(&ws[nb][n2 * 64 + ((g ^ (n2 & 7)) * 8)]) = v;
      }
    }
    // compute on current buffers
    const int arow = 16 * w + l15;
    short8 a0 = *reinterpret_cast<const short8*>(
        &xs[cb][arow * 64 + (((0 + lg) ^ (arow & 7)) * 8)]);
    short8 a1 = *reinterpret_cast<const short8*>(
        &xs[cb][arow * 64 + (((4 + lg) ^ (arow & 7)) * 8)]);
#pragma unroll
    for (int nt = 0; nt < 12; ++nt) {
      int n2 = 16 * nt + l15;
      short8 b0 = *reinterpret_cast<const short8*>(
          &ws[cb][n2 * 64 + (((0 + lg) ^ (n2 & 7)) * 8)]);
      short8 b1 = *reinterpret_cast<const short8*>(
          &ws[cb][n2 * 64 + (((4 + lg) ^ (n2 & 7)) * 8)]);
      acc[nt] = __builtin_amdgcn_mfma_f32_16x16x32_bf16(a0, b0, acc[nt], 0, 0, 0);
      acc[nt] = __builtin_amdgcn_mfma_f32_16x16x32_bf16(a1, b1, acc[nt], 0, 0, 0);
    }
    // convert + stage next x
    if (it < 15) {
#pragma unroll
      for (int half = 0; half < 2; ++half) {
        const float* xv = reinterpret_cast<const float*>(&xr4[half * 2]);
        short8 o;
#pragma unroll
        for (int i = 0; i < 8; ++i) o[i] = f2bf(xv[i]);
        int g = xg0 + half;
        *reinterpret_cast<short8*>(&xs[nb][xr * 64 + ((g ^ (xr & 7)) * 8)]) = o;
      }
    }
  }

  // ---- epilogue ----
  // K, Q: row-major bf16 stores. D layout: row=(lg*4+r), col=l15 per n-tile.
  const int orow = rbase + 16 * w;
#pragma unroll
  for (int nt = 0; nt < 4; ++nt) {
#pragma unroll
    for (int r = 0; r < 4; ++r) {
      int row = orow + lg * 4 + r;
      Kp[(size_t)row * H_ + nt * 16 + l15] = f2bf(acc[nt][r]);
      Qp[(size_t)row * H_ + nt * 16 + l15] = f2bf(acc[4 + nt][r]);
    }
  }
  // V: transpose through LDS -> Vt[b][h][t]
  __syncthreads();
  short* vl = &xs[0][0];  // 4096 shorts available; need 32*66
#pragma unroll
  for (int nt = 0; nt < 4; ++nt) {
#pragma unroll
    for (int r = 0; r < 4; ++r) {
      int rl = 16 * w + lg * 4 + r;
      vl[rl * 66 + nt * 16 + l15] = f2bf(acc[8 + nt][r]);
    }
  }
  __syncthreads();
  {
    const int h = t >> 1, half = t & 1;
    short8 o0, o1;
#pragma unroll
    for (int i = 0; i < 8; ++i) o0[i] = vl[(half * 16 + i) * 66 + h];
#pragma unroll
    for (int i = 0; i < 8; ++i) o1[i] = vl[(half * 16 + 8 + i) * 66 + h];
    const int b = rbase >> 11, tb = rbase & 2047;
    short* dst = &Vt[(size_t)b * H_ * T_ + (size_t)h * T_ + tb + half * 16];
    *reinterpret_cast<short8*>(dst) = o0;
    *reinterpret_cast<short8*>(dst + 8) = o1;
  }
}

// ---------------------------------------------------------------------------
// attn: causal flash attention, bf16 MFMA. Attention-query = Kp, key = Qp.
// 256 blocks x 128 thr; each WAVE is an independent flash unit handling the
// balanced pair of 16-row q-tiles (u, 127-u) -> 33-34 k-iters/wave, no syncs.
// KBLK=64. Fragments loaded directly from L2-resident K/Q/Vt; P staged via
// 2KB XOR-swizzled LDS per wave.
// ---------------------------------------------------------------------------
__global__ __launch_bounds__(128) void attn_kernel(
    const short* __restrict__ Kq, const short* __restrict__ Qk,
    const short* __restrict__ Vt, float* __restrict__ out) {
  __shared__ short Ps[2][16 * 64];
  const int t = threadIdx.x, w = t >> 6, lane = t & 63;
  const int l15 = lane & 15, lg = lane >> 4;
  const int batch = blockIdx.x >> 5;
  const int pp = ((blockIdx.x & 31) << 1) | w;  // 0..63
  const short* Kb = Kq + (size_t)batch * T_ * H_;
  const short* Qb = Qk + (size_t)batch * T_ * H_;
  const short* Vb = Vt + (size_t)batch * H_ * T_;
  float* ob = out + (size_t)batch * T_ * H_;
  short* ps = &Ps[w][0];
  const f32x4 zf = {0.f, 0.f, 0.f, 0.f};

#pragma unroll 1
  for (int uu = 0; uu < 2; ++uu) {
    const int u = uu ? (127 - pp) : pp;  // 16-row q-tile index
    const int qbase = u * 16;
    const short* qp = &Kb[(size_t)(qbase + l15) * H_ + lg * 8];
    short8 qa0 = *reinterpret_cast<const short8*>(qp);
    short8 qa1 = *reinterpret_cast<const short8*>(qp + 32);
    f32x4 O[4];
    float m[4], l[4];
#pragma unroll
    for (int i = 0; i < 4; ++i) { O[i] = zf; m[i] = -1e30f; l[i] = 0.f; }
    const int nkt = (u >> 2) + 1;

    for (int kt = 0; kt < nkt; ++kt) {
      const int kbase = kt * 64;
      f32x4 S[4];
#pragma unroll
      for (int i = 0; i < 4; ++i) S[i] = zf;
      // QK^T: S[q 16][k 64]
#pragma unroll
      for (int nt = 0; nt < 4; ++nt) {
        const short* kp = &Qb[(size_t)(kbase + 16 * nt + l15) * H_ + lg * 8];
        short8 kb0 = *reinterpret_cast<const short8*>(kp);
        short8 kb1 = *reinterpret_cast<const short8*>(kp + 32);
        S[nt] = __builtin_amdgcn_mfma_f32_16x16x32_bf16(qa0, kb0, S[nt], 0, 0, 0);
        S[nt] = __builtin_amdgcn_mfma_f32_16x16x32_bf16(qa1, kb1, S[nt], 0, 0, 0);
      }
      const bool last = (kt == nkt - 1);
      // scale + causal mask + row max (rows live on 16-lane groups)
      float rmax[4];
#pragma unroll
      for (int r = 0; r < 4; ++r) {
#pragma unroll
        for (int nt = 0; nt < 4; ++nt) {
          float s = S[nt][r] * 0.03125f;  // 1024^-0.5
          if (last && (kbase + 16 * nt + l15 > qbase + lg * 4 + r)) s = -1e30f;
          S[nt][r] = s;
        }
        float mx = fmaxf(fmaxf(S[0][r], S[1][r]), fmaxf(S[2][r], S[3][r]));
        mx = fmaxf(mx, __shfl_xor(mx, 1));
        mx = fmaxf(mx, __shfl_xor(mx, 2));
        mx = fmaxf(mx, __shfl_xor(mx, 4));
        mx = fmaxf(mx, __shfl_xor(mx, 8));
        rmax[r] = mx;
      }
      // online softmax + stage P (bf16) into swizzled LDS
#pragma unroll
      for (int r = 0; r < 4; ++r) {
        float mn = fmaxf(m[r], rmax[r]);
        float sc = __expf(m[r] - mn);
        m[r] = mn;
        float rs = 0.f;
#pragma unroll
        for (int nt = 0; nt < 4; ++nt) {
          float p = __expf(S[nt][r] - mn);
          S[nt][r] = p;
          rs += p;
        }
        rs += __shfl_xor(rs, 1);
        rs += __shfl_xor(rs, 2);
        rs += __shfl_xor(rs, 4);
        rs += __shfl_xor(rs, 8);
        l[r] = l[r] * sc + rs;
#pragma unroll
        for (int nt = 0; nt < 4; ++nt) O[nt][r] *= sc;
        const int row = lg * 4 + r;
#pragma unroll
        for (int nt = 0; nt < 4; ++nt)
          ps[row * 64 + ((16 * nt + l15) ^ ((row & 7) << 3))] = f2bf(S[nt][r]);
      }
      // PV: O += P[16x64] x V[64x64]
#pragma unroll
      for (int kc = 0; kc < 2; ++kc) {
        short8 pa = *reinterpret_cast<const short8*>(
            &ps[l15 * 64 + ((kc * 32 + lg * 8) ^ ((l15 & 7) << 3))]);
#pragma unroll
        for (int nt = 0; nt < 4; ++nt) {
          short8 vb = *reinterpret_cast<const short8*>(
              &Vb[(size_t)(16 * nt + l15) * T_ + kbase + kc * 32 + lg * 8]);
          O[nt] = __builtin_amdgcn_mfma_f32_16x16x32_bf16(pa, vb, O[nt], 0, 0, 0);
        }
      }
    }
    // epilogue: divide by l, store fp32
#pragma unroll
    for (int r = 0; r < 4; ++r) {
      float iv = 1.0f / l[r];
      int row = qbase + lg * 4 + r;
#pragma unroll
      for (int nt = 0; nt < 4; ++nt)
        ob[(size_t)row * H_ + 16 * nt + l15] = O[nt][r] * iv;
    }
  }
}

extern "C" void kernel_launch(void* const* d_in, const int* in_sizes, int n_in,
                              void* d_out, int out_size, void* d_ws, size_t ws_size,
                              hipStream_t stream) {
  const float* x = (const float*)d_in[0];
  const float* Wk = (const float*)d_in[1];
  const float* Wq = (const float*)d_in[2];
  const float* Wv = (const float*)d_in[3];
  float* out = (float*)d_out;

  short* Kp = (short*)d_ws;                  // [BT][64] bf16 (queries: x@Wk)
  short* Qp = Kp + (size_t)BT_ * H_;         // [BT][64] bf16 (keys:    x@Wq)
  short* Vt = Qp + (size_t)BT_ * H_;         // [8][64][2048] bf16 (values^T)
  short* Wt = Vt + (size_t)BT_ * H_;         // [192][1024] bf16

  hipLaunchKernelGGL(prep_w, dim3(48), dim3(256), 0, stream, Wk, Wq, Wv, Wt);
  hipLaunchKernelGGL(proj_kernel, dim3(512), dim3(128), 0, stream, x, Wt, Kp, Qp, Vt);
  hipLaunchKernelGGL(attn_kernel, dim3(256), dim3(128), 0, stream, Kp, Qp, Vt, out);
}